// Round 12
// baseline (44.208 us; speedup 1.0000x reference)
//
#include <hip/hip_runtime.h>

// out[b,n] = q^T W_n p ; p=emb[b,R(n)], q=emb[b,C(n)], W_n=kern[:,n,:]
// R12: no LDS, no barriers in main. Prep writes THREE fragment-ordered tables:
//   kb : W   in 16x16x32 A-frag order [n][mh*2+kc][lane][8]         (~3.9MB)
//   ebp: emb in B-frag order          [f][bt16][kc][lane][8]        (8MB)
//   ebq: emb in C/D-matched q order   [f][bt16][half][lane][8]      (8MB)
// Main: wave = 1 pair x 128 b (8 chunks of 16). Per chunk: 4 coalesced 1KB
// loads + 8 MFMA + 16 FMA + 2 shfl + store. ~80 VGPR -> ~6 waves/SIMD.

#define B_TOT 2048
#define NF    32
#define EMB   64
#define NP    496

typedef short bf16x8 __attribute__((ext_vector_type(8)));
typedef float f32x4  __attribute__((ext_vector_type(4)));

static __device__ inline unsigned f2bf(float f) {          // RNE f32->bf16
    unsigned u = __builtin_bit_cast(unsigned, f);
    u += 0x7fffu + ((u >> 16) & 1u);
    return u >> 16;
}
static __device__ inline unsigned pack2(float lo, float hi) {
    return f2bf(lo) | (f2bf(hi) << 16);
}
static __device__ inline float bf2f(short s) {
    return __builtin_bit_cast(float, (unsigned)((unsigned short)s) << 16);
}

// ---- fused prep, grid-split:
//  [0,496)        : kern -> kb  (16x16x32 A-fragment order, via LDS transpose)
//  [496,2544)     : emb  -> ebp (B-fragment order)
//  [2544,3568)    : emb  -> ebq (C/D-matched q order)
__global__ __launch_bounds__(256) void prep(const float* __restrict__ kern,
                                            const float* __restrict__ emb,
                                            short* __restrict__ kb,
                                            short* __restrict__ ebp,
                                            short* __restrict__ ebq) {
    __shared__ short w[EMB * 72];
    const int bid = blockIdx.x, tid = threadIdx.x;
    if (bid < NP) {
        const int n = bid;
#pragma unroll
        for (int j = 0; j < 4; ++j) {
            const int idx = tid + 256 * j;            // (h, e4)
            const int h = idx >> 4, e4 = idx & 15;
            const f32x4 v = *(const f32x4*)(kern + ((size_t)h * NP + n) * EMB + e4 * 4);
            uint2 u;
            u.x = pack2(v[0], v[1]);
            u.y = pack2(v[2], v[3]);
            *(uint2*)&w[h * 72 + e4 * 4] = u;
        }
        __syncthreads();
#pragma unroll
        for (int j = 0; j < 2; ++j) {
            const int u    = tid + 256 * j;           // fragment-lane unit
            const int frag = u >> 6, l = u & 63;
            const int h  = (frag >> 1) * 16 + (l & 15);
            const int e0 = (frag & 1) * 32 + (l >> 4) * 8;
            const bf16x8 t = *(const bf16x8*)&w[h * 72 + e0];
            *(bf16x8*)(kb + (size_t)n * 4096 + u * 8) = t;
        }
    } else if (bid < NP + 2048) {
        // ebp unit u: l=u&63, kc=(u>>6)&1, bt=(u>>7)&127, f=u>>14
        const int u  = (bid - NP) * 256 + tid;
        const int l  = u & 63, kc = (u >> 6) & 1;
        const int bt = (u >> 7) & 127, f = (u >> 14) & 31;
        const int b  = bt * 16 + (l & 15);
        const int e0 = kc * 32 + (l >> 4) * 8;
        const float* src = emb + ((size_t)b * NF + f) * EMB + e0;
        const f32x4 a = *(const f32x4*)src;
        const f32x4 c = *(const f32x4*)(src + 4);
        uint4 o;
        o.x = pack2(a[0], a[1]); o.y = pack2(a[2], a[3]);
        o.z = pack2(c[0], c[1]); o.w = pack2(c[2], c[3]);
        *(uint4*)(ebp + (size_t)u * 8) = o;
    } else {
        // ebq unit u (32B): l=u&63, bt=(u>>6)&127, f=u>>13
        const int u  = (bid - NP - 2048) * 256 + tid;
        const int l  = u & 63;
        const int bt = (u >> 6) & 127, f = (u >> 13) & 31;
        const int b   = bt * 16 + (l & 15);
        const int hi4 = l >> 4;
        const float* base = emb + ((size_t)b * NF + f) * EMB + hi4 * 4;
        const f32x4 v0 = *(const f32x4*)(base);          // mh=0: h=hi4*4..
        const f32x4 v1 = *(const f32x4*)(base + 16);     // mh=1
        const f32x4 v2 = *(const f32x4*)(base + 32);     // mh=2
        const f32x4 v3 = *(const f32x4*)(base + 48);     // mh=3
        const size_t fb   = (size_t)f * 128 + bt;
        const size_t off0 = (fb * 2 + 0) * 512 + l * 8;  // half 0: mh 0,1
        uint4 oa, ob;
        oa.x = pack2(v0[0], v0[1]); oa.y = pack2(v0[2], v0[3]);
        oa.z = pack2(v1[0], v1[1]); oa.w = pack2(v1[2], v1[3]);
        ob.x = pack2(v2[0], v2[1]); ob.y = pack2(v2[2], v2[3]);
        ob.z = pack2(v3[0], v3[1]); ob.w = pack2(v3[2], v3[3]);
        *(uint4*)(ebq + off0)       = oa;
        *(uint4*)(ebq + off0 + 512) = ob;                // half 1: mh 2,3
    }
}

__global__ __launch_bounds__(256) void opnl_main(
    const short* __restrict__ ebp,   // [f][bt16][kc][64][8] bf16 B-frag order
    const short* __restrict__ ebq,   // [f][bt16][half][64][8] bf16 q order
    const short* __restrict__ kb,    // [n][8][64][8] bf16 A-frag order
    float* __restrict__ out)         // [B][NP] f32
{
    const int bid = blockIdx.x;
    const int bg  = bid / NP;                // 0..3 (512-b group)
    const int n   = bid - bg * NP;           // pair 0..495

    // decode n -> (R, C)  (scalar, uniform)
    int r = 0, rem = n;
    while (rem >= NF - 1 - r) { rem -= NF - 1 - r; ++r; }
    const int R = r;
    const int C = r + 1 + rem;

    const int lane = threadIdx.x & 63;
    const int wid  = threadIdx.x >> 6;       // 0..3
    const int lo4  = lane & 15;

    // W fragments: 8 coalesced 1KB loads, reused across 128 b
    bf16x8 wf[4][2];
    const bf16x8* wp = (const bf16x8*)(kb + (size_t)n * 4096);
#pragma unroll
    for (int mh = 0; mh < 4; ++mh)
#pragma unroll
        for (int kc = 0; kc < 2; ++kc)
            wf[mh][kc] = wp[(mh * 2 + kc) * 64 + lane];

    const size_t pbase = ((size_t)R * 128) * 1024;   // ebp elems per bt: 2*64*8=1024
    const size_t qbase = ((size_t)C * 128) * 1024;   // ebq elems per bt: 2*512=1024

#pragma unroll 2
    for (int c8 = 0; c8 < 8; ++c8) {
        const int bt  = bg * 32 + wid * 8 + c8;      // 16-b chunk id 0..127
        const int b0c = bt * 16;

        // 4 coalesced 1KB loads (independent -> MLP)
        bf16x8 pf0 = *(const bf16x8*)(ebp + pbase + (size_t)bt * 1024 + (0 * 64 + lane) * 8);
        bf16x8 pf1 = *(const bf16x8*)(ebp + pbase + (size_t)bt * 1024 + (1 * 64 + lane) * 8);
        bf16x8 qd0 = *(const bf16x8*)(ebq + qbase + (size_t)bt * 1024 + 0 * 512 + lane * 8);
        bf16x8 qd1 = *(const bf16x8*)(ebq + qbase + (size_t)bt * 1024 + 1 * 512 + lane * 8);

        f32x4 acc[4] = {f32x4{0,0,0,0}, f32x4{0,0,0,0},
                        f32x4{0,0,0,0}, f32x4{0,0,0,0}};
#pragma unroll
        for (int mh = 0; mh < 4; ++mh) {
            acc[mh] = __builtin_amdgcn_mfma_f32_16x16x32_bf16(wf[mh][0], pf0, acc[mh], 0, 0, 0);
            acc[mh] = __builtin_amdgcn_mfma_f32_16x16x32_bf16(wf[mh][1], pf1, acc[mh], 0, 0, 0);
        }

        // epilogue: lane holds U[h = mh*16 + hi4*4 + i, b=lo4];
        // q(mh,i) = (mh<2 ? qd0 : qd1)[(mh&1)*4 + i]  (table matches C/D layout)
        float v0 = acc[0][0] * bf2f(qd0[0]);
        float v1 = acc[1][0] * bf2f(qd0[4]);
        float v2 = acc[2][0] * bf2f(qd1[0]);
        float v3 = acc[3][0] * bf2f(qd1[4]);
#pragma unroll
        for (int i = 1; i < 4; ++i) {
            v0 = fmaf(acc[0][i], bf2f(qd0[i]),     v0);
            v1 = fmaf(acc[1][i], bf2f(qd0[4 + i]), v1);
            v2 = fmaf(acc[2][i], bf2f(qd1[i]),     v2);
            v3 = fmaf(acc[3][i], bf2f(qd1[4 + i]), v3);
        }
        float val = (v0 + v1) + (v2 + v3);
        val += __shfl_xor(val, 16, 64);
        val += __shfl_xor(val, 32, 64);
        if (lane < 16) out[(size_t)(b0c + lo4) * NP + n] = val;
    }
}

extern "C" void kernel_launch(void* const* d_in, const int* in_sizes, int n_in,
                              void* d_out, int out_size, void* d_ws, size_t ws_size,
                              hipStream_t stream) {
    const float* emb  = (const float*)d_in[0];   // 2048*32*64
    const float* kern = (const float*)d_in[1];   // 64*496*64
    float*       out  = (float*)d_out;           // 2048*496

    short* kb  = (short*)d_ws;                             // ~3.9MB
    short* ebp = (short*)((char*)d_ws + (4  << 20));       // 8MB
    short* ebq = (short*)((char*)d_ws + (12 << 20));       // 8MB

    prep<<<NP + 2048 + 1024, 256, 0, stream>>>(kern, emb, kb, ebp, ebq);
    opnl_main<<<4 * NP, 256, 0, stream>>>(ebp, ebq, kb, out);   // 1984 blocks
}

// Round 14
// 39.297 us; speedup vs baseline: 1.1250x; 1.1250x over previous
//
#include <hip/hip_runtime.h>

// out[b,n] = q^T W_n p ; p=emb[b,R(n)], q=emb[b,C(n)], W_n=kern[:,n,:]
// R14: R8 structure (verified epilogue) +
//  - XCD-pinned types: type = bid&7 -> each XCD's W window ~0.5MB, L2-resident.
//  - consecutive pair ranges per wave + lr-keyed p-fragment cache (16 VGPR):
//    cross types lr==wid (1 p-load/wave); triu types 1-2 loads. Cuts LDS p-reads.
// Layouts identical to R7/R8: kb fragment-ordered, ebf chunk-swizzled,
// global_load_lds staging, W ping-pong dbuf.

#define B_TOT 2048
#define NF    32
#define EMB   64
#define NP    496
#define BT    32

typedef short bf16x8 __attribute__((ext_vector_type(8)));
typedef short bf16x4 __attribute__((ext_vector_type(4)));
typedef float f32x4  __attribute__((ext_vector_type(4)));

static __device__ inline unsigned f2bf(float f) {          // RNE f32->bf16
    unsigned u = __builtin_bit_cast(unsigned, f);
    u += 0x7fffu + ((u >> 16) & 1u);
    return u >> 16;
}
static __device__ inline unsigned pack2(float lo, float hi) {
    return f2bf(lo) | (f2bf(hi) << 16);
}
static __device__ inline float bf2f(short s) {
    return __builtin_bit_cast(float, (unsigned)((unsigned short)s) << 16);
}

#define AS1 __attribute__((address_space(1)))
#define AS3 __attribute__((address_space(3)))

// triu16 pair decode LUT: byte = lr*16 + lc for pig 0..119
__device__ const unsigned char PAIR_T16[120] = {
    0x01,0x02,0x03,0x04,0x05,0x06,0x07,0x08,0x09,0x0A,0x0B,0x0C,0x0D,0x0E,0x0F,
    0x12,0x13,0x14,0x15,0x16,0x17,0x18,0x19,0x1A,0x1B,0x1C,0x1D,0x1E,0x1F,
    0x23,0x24,0x25,0x26,0x27,0x28,0x29,0x2A,0x2B,0x2C,0x2D,0x2E,0x2F,
    0x34,0x35,0x36,0x37,0x38,0x39,0x3A,0x3B,0x3C,0x3D,0x3E,0x3F,
    0x45,0x46,0x47,0x48,0x49,0x4A,0x4B,0x4C,0x4D,0x4E,0x4F,
    0x56,0x57,0x58,0x59,0x5A,0x5B,0x5C,0x5D,0x5E,0x5F,
    0x67,0x68,0x69,0x6A,0x6B,0x6C,0x6D,0x6E,0x6F,
    0x78,0x79,0x7A,0x7B,0x7C,0x7D,0x7E,0x7F,
    0x89,0x8A,0x8B,0x8C,0x8D,0x8E,0x8F,
    0x9A,0x9B,0x9C,0x9D,0x9E,0x9F,
    0xAB,0xAC,0xAD,0xAE,0xAF,
    0xBC,0xBD,0xBE,0xBF,
    0xCD,0xCE,0xCF,
    0xDE,0xDF,
    0xEF
};

// ---- fused prep: blocks [0,496) = kern cvt ; blocks [496, 496+2048) = emb cvt
__global__ __launch_bounds__(256) void prep(const float* __restrict__ kern,
                                            const float* __restrict__ emb,
                                            short* __restrict__ kb,
                                            short* __restrict__ ebf) {
    __shared__ short w[EMB * 72];
    if (blockIdx.x < NP) {
        const int n = blockIdx.x;
#pragma unroll
        for (int j = 0; j < 4; ++j) {
            const int idx = threadIdx.x + 256 * j;        // (h, e4)
            const int h = idx >> 4, e4 = idx & 15;
            const f32x4 v = *(const f32x4*)(kern + ((size_t)h * NP + n) * EMB + e4 * 4);
            uint2 u;
            u.x = pack2(v[0], v[1]);
            u.y = pack2(v[2], v[3]);
            *(uint2*)&w[h * 72 + e4 * 4] = u;
        }
        __syncthreads();
#pragma unroll
        for (int j = 0; j < 2; ++j) {
            const int u    = threadIdx.x + 256 * j;       // fragment-lane unit
            const int frag = u >> 6, l = u & 63;
            const int h  = (frag >> 1) * 16 + (l & 15);
            const int e0 = (frag & 1) * 32 + (l >> 4) * 8;
            const bf16x8 t = *(const bf16x8*)&w[h * 72 + e0];
            *(bf16x8*)(kb + (size_t)n * 4096 + u * 8) = t;
        }
    } else {
        // emb -> chunk-swizzled bf16
        const int t    = (blockIdx.x - NP) * 256 + threadIdx.x;  // 0..524287
        const int cidx = t & 127;
        const int f    = (t >> 7) & 31;
        const int bt16 = t >> 12;
        const int bp = cidx >> 3, x = cidx & 7;
        const int ec = x ^ (bp & 7);
        const float* src = emb + (((size_t)(bt16 * 16 + bp) * NF + f) * EMB + ec * 8);
        const f32x4 a = *(const f32x4*)src;
        const f32x4 b = *(const f32x4*)(src + 4);
        uint4 u;
        u.x = pack2(a[0], a[1]); u.y = pack2(a[2], a[3]);
        u.z = pack2(b[0], b[1]); u.w = pack2(b[2], b[3]);
        *(uint4*)(ebf + (size_t)t * 8) = u;
    }
}

__global__ __launch_bounds__(512, 4) void opnl_main(
    const short* __restrict__ ebf,   // [B/16][NF][128 chunks x 8 shorts] swizzled
    const short* __restrict__ kb,    // [NP][8][64][8] bf16 fragment order
    float* __restrict__ out)         // [B][NP] f32
{
    __shared__ short elds[16 * 2 * 1024];    // 32 segs x 2KB = 64KB

    const int type = blockIdx.x & 7;         // one type per XCD -> W L2-pinned
    const int bt   = blockIdx.x >> 3;        // 0..63
    const int b0   = bt * BT;

    int bLo, bHi, npr;
    switch (type) {
        case 0: case 1: bLo = 0;  bHi = 0;  npr = 60; break;  // fields 0..15
        case 2: case 3: bLo = 16; bHi = 16; npr = 60; break;  // fields 16..31
        case 4:         bLo = 0;  bHi = 8;  npr = 64; break;
        case 5:         bLo = 8;  bHi = 16; npr = 64; break;
        case 6:         bLo = 0;  bHi = 16; npr = 64; break;
        default:        bLo = 8;  bHi = 8;  npr = 64; break;
    }

    const int lane = threadIdx.x & 63;
    const int wid  = threadIdx.x >> 6;       // 0..7
    const int lo4  = lane & 15;
    const int hi4  = lane >> 4;

    // ---- stage: wave w copies segs 4w..4w+3 (seg = lf*2+sub), 2x 1KB each
#pragma unroll
    for (int i = 0; i < 4; ++i) {
        const int s   = wid * 4 + i;
        const int lf  = s >> 1, sub = s & 1;
        const int gf  = lf + (lf < 8 ? bLo : bHi);
        const short* src = ebf + ((size_t)((bt * 2 + sub) * 32 + gf)) * 1024;
        __builtin_amdgcn_global_load_lds((const AS1 void*)(src + lane * 8),
                                         (AS3 void*)&elds[s * 1024], 16, 0, 0);
        __builtin_amdgcn_global_load_lds((const AS1 void*)(src + 512 + lane * 8),
                                         (AS3 void*)&elds[s * 1024 + 512], 16, 0, 0);
    }
    __syncthreads();

    // consecutive pair range per wave -> lr mostly constant within a wave
    const int s_ = (wid * npr) >> 3;
    const int e_ = ((wid + 1) * npr) >> 3;

    auto pairK = [&](int k, int& lr, int& lc, int& nn) {
        int pr = s_ + k;
        if (pr >= e_) pr = s_;               // pad: benign duplicate of own pair
        if (type < 4) {
            const int pig = __builtin_amdgcn_readfirstlane((type & 1) * 60 + pr);
            const int byt = PAIR_T16[pig];
            lr = byt >> 4; lc = byt & 15;
        } else {
            lr = pr >> 3; lc = 8 + (pr & 7); // lr == wid (constant per wave)
        }
        const int R = lr + (lr < 8 ? bLo : bHi);
        const int C = lc + (lc < 8 ? bLo : bHi);
        nn = R * (63 - R) / 2 + (C - R - 1);
    };

    auto loadW = [&](bf16x8 (&wf)[4][2], int nn) {
        const bf16x8* wp = (const bf16x8*)(kb + (size_t)nn * 4096);
#pragma unroll
        for (int mh = 0; mh < 4; ++mh)
#pragma unroll
            for (int kc = 0; kc < 2; ++kc)
                wf[mh][kc] = wp[(mh * 2 + kc) * 64 + lane];   // 1KB coalesced
    };

    // p-fragment cache, keyed on lr (wave-uniform reload)
    bf16x8 pfc[2][2];
    int lr_prev = -1;
    auto loadP = [&](int lr) {
        if (lr == lr_prev) return;
        lr_prev = lr;
#pragma unroll
        for (int sub = 0; sub < 2; ++sub)
#pragma unroll
            for (int kc = 0; kc < 2; ++kc)
                pfc[sub][kc] = *(const bf16x8*)
                    &elds[(lr * 2 + sub) * 1024 +
                          (lo4 * 8 + ((kc * 4 + hi4) ^ (lo4 & 7))) * 8];
    };

    auto compute = [&](bf16x8 (&wf)[4][2], int lc, int nn) {
#pragma unroll
        for (int sub = 0; sub < 2; ++sub) {
            const int bb = sub * 16 + lo4;

            // q reads: 4 b64 (hoisted)
            bf16x4 q0 = *(const bf16x4*)
                &elds[(lc * 2 + sub) * 1024 + (lo4 * 8 + ((0 + (hi4 >> 1)) ^ (lo4 & 7))) * 8 + (hi4 & 1) * 4];
            bf16x4 q1 = *(const bf16x4*)
                &elds[(lc * 2 + sub) * 1024 + (lo4 * 8 + ((2 + (hi4 >> 1)) ^ (lo4 & 7))) * 8 + (hi4 & 1) * 4];
            bf16x4 q2 = *(const bf16x4*)
                &elds[(lc * 2 + sub) * 1024 + (lo4 * 8 + ((4 + (hi4 >> 1)) ^ (lo4 & 7))) * 8 + (hi4 & 1) * 4];
            bf16x4 q3 = *(const bf16x4*)
                &elds[(lc * 2 + sub) * 1024 + (lo4 * 8 + ((6 + (hi4 >> 1)) ^ (lo4 & 7))) * 8 + (hi4 & 1) * 4];

            f32x4 acc[4] = {f32x4{0,0,0,0}, f32x4{0,0,0,0},
                            f32x4{0,0,0,0}, f32x4{0,0,0,0}};
            __builtin_amdgcn_s_setprio(1);
#pragma unroll
            for (int mh = 0; mh < 4; ++mh) {
                acc[mh] = __builtin_amdgcn_mfma_f32_16x16x32_bf16(
                    wf[mh][0], pfc[sub][0], acc[mh], 0, 0, 0);
                acc[mh] = __builtin_amdgcn_mfma_f32_16x16x32_bf16(
                    wf[mh][1], pfc[sub][1], acc[mh], 0, 0, 0);
            }
            __builtin_amdgcn_s_setprio(0);

            // epilogue: 4 independent partial dots, tree combine (R8-verified)
            float v0 = acc[0][0] * bf2f(q0[0]);
            float v1 = acc[1][0] * bf2f(q1[0]);
            float v2 = acc[2][0] * bf2f(q2[0]);
            float v3 = acc[3][0] * bf2f(q3[0]);
            v0 = fmaf(acc[0][1], bf2f(q0[1]), v0);
            v1 = fmaf(acc[1][1], bf2f(q1[1]), v1);
            v2 = fmaf(acc[2][1], bf2f(q2[1]), v2);
            v3 = fmaf(acc[3][1], bf2f(q3[1]), v3);
            v0 = fmaf(acc[0][2], bf2f(q0[2]), v0);
            v1 = fmaf(acc[1][2], bf2f(q1[2]), v1);
            v2 = fmaf(acc[2][2], bf2f(q2[2]), v2);
            v3 = fmaf(acc[3][2], bf2f(q3[2]), v3);
            v0 = fmaf(acc[0][3], bf2f(q0[3]), v0);
            v1 = fmaf(acc[1][3], bf2f(q1[3]), v1);
            v2 = fmaf(acc[2][3], bf2f(q2[3]), v2);
            v3 = fmaf(acc[3][3], bf2f(q3[3]), v3);
            float val = (v0 + v1) + (v2 + v3);

            val += __shfl_xor(val, 16, 64);
            val += __shfl_xor(val, 32, 64);
            if (lane < 16) out[(size_t)(b0 + bb) * NP + nn] = val;
        }
    };

    // ---- 8 pairs per wave, W ping-pong double-buffered (static buffers)
    bf16x8 wA[4][2], wB[4][2];
    int lrA, lcA, nA, lrB, lcB, nB;
    pairK(0, lrA, lcA, nA);
    loadW(wA, nA);
#pragma unroll
    for (int k = 0; k < 8; ++k) {
        if ((k & 1) == 0) {
            if (k < 7) { pairK(k + 1, lrB, lcB, nB); loadW(wB, nB); }
            loadP(lrA); compute(wA, lcA, nA);
        } else {
            if (k < 7) { pairK(k + 1, lrA, lcA, nA); loadW(wA, nA); }
            loadP(lrB); compute(wB, lcB, nB);
        }
    }
}

extern "C" void kernel_launch(void* const* d_in, const int* in_sizes, int n_in,
                              void* d_out, int out_size, void* d_ws, size_t ws_size,
                              hipStream_t stream) {
    const float* emb  = (const float*)d_in[0];   // 2048*32*64
    const float* kern = (const float*)d_in[1];   // 64*496*64
    float*       out  = (float*)d_out;           // 2048*496

    short* kb  = (short*)d_ws;                          // 496*4096 bf16 ~3.9MB
    short* ebf = (short*)((char*)d_ws + (4 << 20));     // 2048*32*64 bf16 = 8MB

    prep<<<NP + (B_TOT * NF * EMB / 8) / 256, 256, 0, stream>>>(kern, emb, kb, ebf);
    opnl_main<<<8 * 64, 512, 0, stream>>>(ebf, kb, out);   // 512 blocks
}